// Round 15
// baseline (110.100 us; speedup 1.0000x reference)
//
#include <hip/hip_runtime.h>
#include <hip/hip_bf16.h>

// C[1024,16384] = l2norm_rows(inputs[1024,2048]) @ features[16384,2048]^T / 0.05
// Round 15: 256x128 tile, BK=32, 48 KB LDS -> grid 512 = 2 blocks/CU.
// Mechanism: cross-block TLP hides barrier/vmcnt drains (m114). LDS
// slot/stage pattern byte-identical to R5/R8 (measured 0 conflicts).

typedef short bf16x8 __attribute__((ext_vector_type(8)));
typedef float f32x4  __attribute__((ext_vector_type(4)));

#define D_K   2048
#define N_N   16384
#define M_M   1024
#define TEMP_INV 20.0f

__device__ __forceinline__ unsigned short f2bf(float f) {
    unsigned u = __builtin_bit_cast(unsigned, f);
    u += 0x7FFFu + ((u >> 16) & 1u);   // round-to-nearest-even (finite data)
    return (unsigned short)(u >> 16);
}

#define GLOAD16(g, l) __builtin_amdgcn_global_load_lds(                        \
    (const __attribute__((address_space(1))) unsigned int*)(g),                \
    (__attribute__((address_space(3))) unsigned int*)(l), 16, 0, 0)

// ---------------- pass 1: prep = anorm (blocks 0..1023) + bconv (rest) ----
__global__ __launch_bounds__(256) void prep_kernel(const float* __restrict__ x,
                                                   const float* __restrict__ B,
                                                   unsigned short* __restrict__ abf,
                                                   unsigned short* __restrict__ bbf) {
    int t = threadIdx.x;
    if (blockIdx.x < M_M) {
        int row = blockIdx.x;
        const float4* xr = reinterpret_cast<const float4*>(x + (size_t)row * D_K);
        float4 a = xr[t * 2];
        float4 b = xr[t * 2 + 1];
        float s = a.x*a.x + a.y*a.y + a.z*a.z + a.w*a.w
                + b.x*b.x + b.y*b.y + b.z*b.z + b.w*b.w;
        #pragma unroll
        for (int off = 32; off > 0; off >>= 1) s += __shfl_down(s, off);
        __shared__ float ps[4];
        __shared__ float sbc;
        if ((t & 63) == 0) ps[t >> 6] = s;
        __syncthreads();
        if (t == 0) {
            float tot = ps[0] + ps[1] + ps[2] + ps[3];
            sbc = 1.0f / fmaxf(sqrtf(tot), 1e-12f);
        }
        __syncthreads();
        float rs = sbc;
        bf16x8 v;
        v[0] = (short)f2bf(a.x * rs); v[1] = (short)f2bf(a.y * rs);
        v[2] = (short)f2bf(a.z * rs); v[3] = (short)f2bf(a.w * rs);
        v[4] = (short)f2bf(b.x * rs); v[5] = (short)f2bf(b.y * rs);
        v[6] = (short)f2bf(b.z * rs); v[7] = (short)f2bf(b.w * rs);
        *reinterpret_cast<bf16x8*>(abf + (size_t)row * D_K + t * 8) = v;
    } else {
        const size_t nv = (size_t)N_N * D_K / 8;
        size_t stride = (size_t)(gridDim.x - M_M) * blockDim.x;
        for (size_t v = (size_t)(blockIdx.x - M_M) * blockDim.x + t; v < nv; v += stride) {
            const float4* p = reinterpret_cast<const float4*>(B) + v * 2;
            float4 a = p[0], b = p[1];
            bf16x8 o;
            o[0] = (short)f2bf(a.x); o[1] = (short)f2bf(a.y);
            o[2] = (short)f2bf(a.z); o[3] = (short)f2bf(a.w);
            o[4] = (short)f2bf(b.x); o[5] = (short)f2bf(b.y);
            o[6] = (short)f2bf(b.z); o[7] = (short)f2bf(b.w);
            reinterpret_cast<bf16x8*>(bbf)[v] = o;
        }
    }
}

// ---------------- pass 2: 256x128 GEMM, BK=32, 2 blocks/CU ----------------
// 512 threads = 8 waves (4M x 2N); wave tile 64x64 = 4x4 16x16 frags.
// LDS 48 KB = buf[2] x {A 16K, B 8K}; row layout row*64B, verified slots.
// Per K-tile T (64 tiles, buf b=T&1):
//   8 ds_read -> lgkmcnt(0) -> barrier (all waves' reads of buf b done)
//   -> stage T+2 -> buf b (3 GLOAD16; WAR-safe) -> 16 MFMA (regs ready)
//   -> vmcnt(3) (retires stage(T+1); stage(T+2) stays in flight) -> barrier.
// Ledger: 3 ops/tile, peak 6 outstanding; prologue leaves stage(1) in
// flight = steady-state entry. Tail clamp writes dead regions only.
__global__ __launch_bounds__(512, 4) void gemmo_kernel(const unsigned short* __restrict__ Abf,
                                                       const unsigned short* __restrict__ Bbf,
                                                       float* __restrict__ C) {
    __shared__ __align__(16) unsigned short lds[24576];   // 48 KiB

    // 512 wgs = 4 Mtiles x 128 Ntiles; bijective XCD swizzle (512 % 8 == 0).
    // 4 consecutive wgs share the same B panel -> same-XCD L2 reuse.
    int bid = blockIdx.x;
    int wg  = (bid & 7) * 64 + (bid >> 3);
    int tm  = wg & 3, tn = wg >> 2;
    int m_blk = tm * 256, n_blk = tn * 128;

    int t = threadIdx.x, lane = t & 63, w = t >> 6;
    int wm = w >> 1, wn = w & 1;                     // 4 x 2 wave grid

    // ds_read lane constants (R5/R8-verified): slot = q ^ ((row>>1)&3)
    int l15  = lane & 15;
    int slot = ((lane >> 4) ^ ((l15 >> 1) & 3)) * 16;
    int aoff[4], boff[4];
    #pragma unroll
    for (int rb = 0; rb < 4; ++rb)
        aoff[rb] = (wm * 64 + rb * 16 + l15) * 64 + slot;
    #pragma unroll
    for (int cb = 0; cb < 4; ++cb)
        boff[cb] = 16384 + (wn * 64 + cb * 16 + l15) * 64 + slot;

    // stage sources (pre-swizzled global chunk, rule #21), linear LDS dest
    int r0 = t >> 2;
    int csrc = (t & 3) ^ ((r0 >> 1) & 3);
    const unsigned short* gA0 = Abf + (size_t)(m_blk + r0) * D_K + csrc * 8;
    const unsigned short* gA1 = Abf + (size_t)(m_blk + 128 + r0) * D_K + csrc * 8;
    const unsigned short* gB0 = Bbf + (size_t)(n_blk + r0) * D_K + csrc * 8;
    int sdst = w * 1024;   // wave-uniform LDS dest base

    // stage K-tile kt (A 16K rows 0-255, B 8K) into buffer b: 3 ops
    auto stage = [&](int b, int ktile) {
        int kt = ktile < 64 ? ktile : 63;              // tail clamp (dead regions)
        int ke = kt * 32;
        char* dst = (char*)lds + b * 24576;
        GLOAD16(gA0 + ke, dst + sdst);
        GLOAD16(gA1 + ke, dst + 8192 + sdst);
        GLOAD16(gB0 + ke, dst + 16384 + sdst);
    };

    f32x4 acc[4][4] = {};

    // prologue: tile0 -> buf0, tile1 -> buf1; vmcnt(3) retires tile0
    stage(0, 0);
    stage(1, 1);
    asm volatile("s_waitcnt vmcnt(3)" ::: "memory");
    asm volatile("s_barrier" ::: "memory");

    for (int T = 0; T < 64; ++T) {
        int b = T & 1;
        char* base = (char*)lds + b * 24576;

        bf16x8 af[4], bv[4];
        #pragma unroll
        for (int rb = 0; rb < 4; ++rb)
            af[rb] = *reinterpret_cast<const bf16x8*>(base + aoff[rb]);
        #pragma unroll
        for (int cb = 0; cb < 4; ++cb)
            bv[cb] = *reinterpret_cast<const bf16x8*>(base + boff[cb]);

        asm volatile("s_waitcnt lgkmcnt(0)" ::: "memory");
        __builtin_amdgcn_sched_barrier(0);
        asm volatile("s_barrier" ::: "memory");        // all reads of buf b done

        stage(b, T + 2);                               // WAR-safe overwrite

        __builtin_amdgcn_s_setprio(1);
        #pragma unroll
        for (int rb = 0; rb < 4; ++rb)
            #pragma unroll
            for (int cb = 0; cb < 4; ++cb)
                acc[rb][cb] = __builtin_amdgcn_mfma_f32_16x16x32_bf16(
                    af[rb], bv[cb], acc[rb][cb], 0, 0, 0);
        __builtin_amdgcn_s_setprio(0);

        asm volatile("s_waitcnt vmcnt(3)" ::: "memory"); // retire stage(T+1)
        asm volatile("s_barrier" ::: "memory");
    }

    // epilogue: C/D layout col=lane&15, row=(lane>>4)*4+j [m89-verified]
    #pragma unroll
    for (int rb = 0; rb < 4; ++rb) {
        int r = m_blk + wm * 64 + rb * 16 + (lane >> 4) * 4;
        #pragma unroll
        for (int j = 0; j < 4; ++j) {
            float* cp = C + (size_t)(r + j) * N_N + n_blk + wn * 64 + l15;
            #pragma unroll
            for (int cb = 0; cb < 4; ++cb)
                cp[cb * 16] = acc[rb][cb][j] * TEMP_INV;
        }
    }
}

// ================= fallback (round-1 fused fp32-staged kernel) ============
__global__ __launch_bounds__(256) void rnorm_kernel(const float* __restrict__ x,
                                                    float* __restrict__ rn) {
    int row = blockIdx.x;
    const float4* xr = reinterpret_cast<const float4*>(x + (size_t)row * D_K);
    int t = threadIdx.x;
    float4 a = xr[t];
    float4 b = xr[t + 256];
    float s = a.x*a.x + a.y*a.y + a.z*a.z + a.w*a.w
            + b.x*b.x + b.y*b.y + b.z*b.z + b.w*b.w;
    #pragma unroll
    for (int off = 32; off > 0; off >>= 1) s += __shfl_down(s, off);
    __shared__ float ps[4];
    int wave = t >> 6, lane = t & 63;
    if (lane == 0) ps[wave] = s;
    __syncthreads();
    if (t == 0) {
        float tot = ps[0] + ps[1] + ps[2] + ps[3];
        rn[row] = 1.0f / fmaxf(sqrtf(tot), 1e-12f);
    }
}

__global__ __launch_bounds__(256, 2) void gemm_kernel(const float* __restrict__ A,
                                                      const float* __restrict__ Bm,
                                                      const float* __restrict__ rn,
                                                      float* __restrict__ C) {
    constexpr int BK = 64;
    __shared__ __align__(16) short lAs[128 * BK];
    __shared__ __align__(16) short lBs[128 * BK];
    int bid = blockIdx.x;
    int nb  = (bid & 7) * 128 + (bid >> 3);
    int tm  = nb & 7;
    int tn  = nb >> 3;
    int m0 = tm * 128, n0 = tn * 128;
    int t = threadIdx.x;
    int lane = t & 63, w = t >> 6;
    int wr = (w >> 1) * 64, wc = (w & 1) * 64;
    f32x4 acc[4][4] = {};
    float4 ra[4][2], rb[4][2];
    float  sc[4];
    int    srow[4], sgrp[4];
    #pragma unroll
    for (int i = 0; i < 4; ++i) {
        int li = t + i * 256;
        srow[i] = li >> 3;
        sgrp[i] = li & 7;
        sc[i]   = rn[m0 + srow[i]];
    }
    auto load_tiles = [&](int kt) {
        int k0 = kt * BK;
        #pragma unroll
        for (int i = 0; i < 4; ++i) {
            const float4* pa = reinterpret_cast<const float4*>(
                A + (size_t)(m0 + srow[i]) * D_K + k0 + sgrp[i] * 8);
            ra[i][0] = pa[0]; ra[i][1] = pa[1];
            const float4* pb = reinterpret_cast<const float4*>(
                Bm + (size_t)(n0 + srow[i]) * D_K + k0 + sgrp[i] * 8);
            rb[i][0] = pb[0]; rb[i][1] = pb[1];
        }
    };
    auto write_tiles = [&]() {
        #pragma unroll
        for (int i = 0; i < 4; ++i) {
            int row = srow[i];
            int slotw = sgrp[i] ^ (row & 7);
            float s = sc[i];
            bf16x8 va, vb;
            va[0] = (short)f2bf(ra[i][0].x * s); va[1] = (short)f2bf(ra[i][0].y * s);
            va[2] = (short)f2bf(ra[i][0].z * s); va[3] = (short)f2bf(ra[i][0].w * s);
            va[4] = (short)f2bf(ra[i][1].x * s); va[5] = (short)f2bf(ra[i][1].y * s);
            va[6] = (short)f2bf(ra[i][1].z * s); va[7] = (short)f2bf(ra[i][1].w * s);
            vb[0] = (short)f2bf(rb[i][0].x); vb[1] = (short)f2bf(rb[i][0].y);
            vb[2] = (short)f2bf(rb[i][0].z); vb[3] = (short)f2bf(rb[i][0].w);
            vb[4] = (short)f2bf(rb[i][1].x); vb[5] = (short)f2bf(rb[i][1].y);
            vb[6] = (short)f2bf(rb[i][1].z); vb[7] = (short)f2bf(rb[i][1].w);
            *reinterpret_cast<bf16x8*>(&lAs[row * BK + slotw * 8]) = va;
            *reinterpret_cast<bf16x8*>(&lBs[row * BK + slotw * 8]) = vb;
        }
    };
    auto compute = [&]() {
        #pragma unroll
        for (int ks = 0; ks < 2; ++ks) {
            bf16x8 af[4], bfr[4];
            #pragma unroll
            for (int f = 0; f < 4; ++f) {
                int arow = wr + f * 16 + (lane & 15);
                int aslot = (ks * 4 + (lane >> 4)) ^ ((arow) & 7);
                af[f] = *reinterpret_cast<const bf16x8*>(&lAs[arow * BK + aslot * 8]);
                int brow = wc + f * 16 + (lane & 15);
                int bslot = (ks * 4 + (lane >> 4)) ^ ((brow) & 7);
                bfr[f] = *reinterpret_cast<const bf16x8*>(&lBs[brow * BK + bslot * 8]);
            }
            #pragma unroll
            for (int m = 0; m < 4; ++m)
                #pragma unroll
                for (int n = 0; n < 4; ++n)
                    acc[m][n] = __builtin_amdgcn_mfma_f32_16x16x32_bf16(
                        af[m], bfr[n], acc[m][n], 0, 0, 0);
        }
    };
    load_tiles(0);
    write_tiles();
    for (int kt = 1; kt < D_K / BK; ++kt) {
        __syncthreads();
        load_tiles(kt);
        compute();
        __syncthreads();
        write_tiles();
    }
    __syncthreads();
    compute();
    #pragma unroll
    for (int m = 0; m < 4; ++m) {
        int r = m0 + wr + m * 16 + (lane >> 4) * 4;
        #pragma unroll
        for (int j = 0; j < 4; ++j) {
            float* cp = C + (size_t)(r + j) * N_N + n0 + wc + (lane & 15);
            #pragma unroll
            for (int n = 0; n < 4; ++n)
                cp[n * 16] = acc[m][n][j] * TEMP_INV;
        }
    }
}

extern "C" void kernel_launch(void* const* d_in, const int* in_sizes, int n_in,
                              void* d_out, int out_size, void* d_ws, size_t ws_size,
                              hipStream_t stream) {
    const float* inputs   = (const float*)d_in[0];
    // d_in[1] = targets (unused by the forward output)
    const float* features = (const float*)d_in[2];
    float* out = (float*)d_out;

    const size_t needA = (size_t)M_M * D_K * 2;           // 4 MiB
    const size_t needB = (size_t)N_N * D_K * 2;           // 64 MiB
    if (ws_size >= needA + needB) {
        unsigned short* Abf = (unsigned short*)d_ws;
        unsigned short* Bbf = Abf + (size_t)M_M * D_K;
        prep_kernel<<<M_M + 2048, 256, 0, stream>>>(inputs, features, Abf, Bbf);
        gemmo_kernel<<<(M_M / 256) * (N_N / 128), 512, 0, stream>>>(Abf, Bbf, out);
    } else {
        float* rn = (float*)d_ws;   // 1024 floats
        rnorm_kernel<<<M_M, 256, 0, stream>>>(inputs, rn);
        gemm_kernel<<<(M_M / 128) * (N_N / 128), 256, 0, stream>>>(inputs, features, rn, out);
    }
}

// Round 16
// 103.660 us; speedup vs baseline: 1.0621x; 1.0621x over previous
//
#include <hip/hip_runtime.h>
#include <hip/hip_bf16.h>

// C[1024,16384] = l2norm_rows(inputs[1024,2048]) @ features[16384,2048]^T / 0.05
// Round 16: R8 pipeline with vmcnt cadence halved — single vmcnt(4) at
// P2-post of each K-tile (was vmcnt(8) at P2 and P4). Ledger re-verified.
// Everything else byte-identical to the best-known R8 kernel (103.8 us).

typedef short bf16x8 __attribute__((ext_vector_type(8)));
typedef float f32x4  __attribute__((ext_vector_type(4)));

#define D_K   2048
#define N_N   16384
#define M_M   1024
#define TEMP_INV 20.0f

__device__ __forceinline__ unsigned short f2bf(float f) {
    unsigned u = __builtin_bit_cast(unsigned, f);
    u += 0x7FFFu + ((u >> 16) & 1u);   // round-to-nearest-even (finite data)
    return (unsigned short)(u >> 16);
}

#define GLOAD16(g, l) __builtin_amdgcn_global_load_lds(                        \
    (const __attribute__((address_space(1))) unsigned int*)(g),                \
    (__attribute__((address_space(3))) unsigned int*)(l), 16, 0, 0)

// ---------------- pass 1: prep = anorm (blocks 0..1023) + bconv (rest) ----
__global__ __launch_bounds__(256) void prep_kernel(const float* __restrict__ x,
                                                   const float* __restrict__ B,
                                                   unsigned short* __restrict__ abf,
                                                   unsigned short* __restrict__ bbf) {
    int t = threadIdx.x;
    if (blockIdx.x < M_M) {
        int row = blockIdx.x;
        const float4* xr = reinterpret_cast<const float4*>(x + (size_t)row * D_K);
        float4 a = xr[t * 2];
        float4 b = xr[t * 2 + 1];
        float s = a.x*a.x + a.y*a.y + a.z*a.z + a.w*a.w
                + b.x*b.x + b.y*b.y + b.z*b.z + b.w*b.w;
        #pragma unroll
        for (int off = 32; off > 0; off >>= 1) s += __shfl_down(s, off);
        __shared__ float ps[4];
        __shared__ float sbc;
        if ((t & 63) == 0) ps[t >> 6] = s;
        __syncthreads();
        if (t == 0) {
            float tot = ps[0] + ps[1] + ps[2] + ps[3];
            sbc = 1.0f / fmaxf(sqrtf(tot), 1e-12f);
        }
        __syncthreads();
        float rs = sbc;
        bf16x8 v;
        v[0] = (short)f2bf(a.x * rs); v[1] = (short)f2bf(a.y * rs);
        v[2] = (short)f2bf(a.z * rs); v[3] = (short)f2bf(a.w * rs);
        v[4] = (short)f2bf(b.x * rs); v[5] = (short)f2bf(b.y * rs);
        v[6] = (short)f2bf(b.z * rs); v[7] = (short)f2bf(b.w * rs);
        *reinterpret_cast<bf16x8*>(abf + (size_t)row * D_K + t * 8) = v;
    } else {
        const size_t nv = (size_t)N_N * D_K / 8;
        size_t stride = (size_t)(gridDim.x - M_M) * blockDim.x;
        for (size_t v = (size_t)(blockIdx.x - M_M) * blockDim.x + t; v < nv; v += stride) {
            const float4* p = reinterpret_cast<const float4*>(B) + v * 2;
            float4 a = p[0], b = p[1];
            bf16x8 o;
            o[0] = (short)f2bf(a.x); o[1] = (short)f2bf(a.y);
            o[2] = (short)f2bf(a.z); o[3] = (short)f2bf(a.w);
            o[4] = (short)f2bf(b.x); o[5] = (short)f2bf(b.y);
            o[6] = (short)f2bf(b.z); o[7] = (short)f2bf(b.w);
            reinterpret_cast<bf16x8*>(bbf)[v] = o;
        }
    }
}

// ---------------- pass 2: 256x256 8-phase GEMM (R8 + 1-wait/tile) ---------
// Ledger: 8 stage-ops issued per K-tile (4 stage calls x 2). Single
// vmcnt(4) at P2-post of tile T: 4 newest = k1(T+1) stay; retires k1(T)
// (read T.P3/P4 after barrier) and k0(T+1) (read T+1.P1/P2). k1(T+1) is
// certified by T+1's P2 wait before its P3 read. WAR unchanged from R8.
__global__ __launch_bounds__(512, 2) void gemm8_kernel(const unsigned short* __restrict__ Abf,
                                                       const unsigned short* __restrict__ Bbf,
                                                       float* __restrict__ C) {
    __shared__ __align__(16) unsigned short lds[65536];   // 128 KiB

    // 256 wgs = 4 Mtiles x 64 Ntiles; bijective XCD swizzle (256 % 8 == 0).
    int bid = blockIdx.x;
    int wg  = (bid & 7) * 32 + (bid >> 3);
    int tm  = wg & 3, tn = wg >> 2;
    int m_blk = tm * 256, n_blk = tn * 256;

    int t = threadIdx.x, lane = t & 63, w = t >> 6;
    int wm = w >> 2, wn = w & 3;                     // 2 x 4 wave grid

    // ds_read lane constants: slot = chunk ^ ((row>>1)&3)
    int l15  = lane & 15;
    int slot = ((lane >> 4) ^ ((l15 >> 1) & 3)) * 16;     // byte slot offset
    int aoff = (wm * 128 + l15) * 64 + slot;              // A region byte off
    int boff = (wn * 64  + l15) * 64 + slot;              // B region byte off

    // stage source pointers (pre-swizzled global chunk per rule #21)
    const unsigned short* gA[2];
    const unsigned short* gB[2];
    int sdst[2];
    #pragma unroll
    for (int pass = 0; pass < 2; ++pass) {
        int r = pass * 128 + (t >> 2);
        int csrc = (t & 3) ^ ((r >> 1) & 3);
        gA[pass] = Abf + (size_t)(m_blk + r) * D_K + csrc * 8;
        gB[pass] = Bbf + (size_t)(n_blk + r) * D_K + csrc * 8;
        sdst[pass] = pass * 8192 + w * 1024;   // wave-uniform LDS dest base
    }

    // stage one half-tile: region (mat, s) of K-tile kt into buffer b
    auto stage = [&](int mat, int s, int b, int ktile) {
        int kt = ktile < 32 ? ktile : 31;              // tail clamp (dead regions)
        int koff = kt * 64 + s * 32;
        int ldsb = b * 65536 + mat * 32768 + s * 16384;
        GLOAD16((mat ? gB[0] : gA[0]) + koff, (char*)lds + ldsb + sdst[0]);
        GLOAD16((mat ? gB[1] : gA[1]) + koff, (char*)lds + ldsb + sdst[1]);
    };

    f32x4 acc[8][4] = {};
    bf16x8 bfr[4];                                     // persists across phase pairs

#define VM4 asm volatile("s_waitcnt vmcnt(4)" ::: "memory")

#define PHASE(b, mh, s, LOADB, stMat, stS, stB, stKt, POST)                    \
    {                                                                          \
        bf16x8 af[4];                                                          \
        _Pragma("unroll")                                                      \
        for (int f = 0; f < 4; ++f)                                            \
            af[f] = *reinterpret_cast<const bf16x8*>(                          \
                (char*)lds + (b) * 65536 + (s) * 16384 + aoff +                \
                ((mh) * 64 + f * 16) * 64);                                    \
        if (LOADB) {                                                           \
            _Pragma("unroll")                                                  \
            for (int n = 0; n < 4; ++n)                                        \
                bfr[n] = *reinterpret_cast<const bf16x8*>(                     \
                    (char*)lds + (b) * 65536 + 32768 + (s) * 16384 + boff +    \
                    n * 1024);                                                 \
        }                                                                      \
        stage(stMat, stS, stB, stKt);                                          \
        asm volatile("s_barrier" ::: "memory");                                \
        asm volatile("s_waitcnt lgkmcnt(0)" ::: "memory");                     \
        __builtin_amdgcn_sched_barrier(0);                                     \
        __builtin_amdgcn_s_setprio(1);                                         \
        _Pragma("unroll")                                                      \
        for (int f = 0; f < 4; ++f) {                                          \
            _Pragma("unroll")                                                  \
            for (int n = 0; n < 4; ++n)                                        \
                acc[(mh) * 4 + f][n] = __builtin_amdgcn_mfma_f32_16x16x32_bf16(\
                    af[f], bfr[n], acc[(mh) * 4 + f][n], 0, 0, 0);             \
        }                                                                      \
        __builtin_amdgcn_s_setprio(0);                                         \
        POST;                                                                  \
        asm volatile("s_barrier" ::: "memory");                                \
    }

    // prologue: K0 full + K1 k0-halves; vmcnt(8) -> oldest 4 ops (K0 k0) landed
    stage(0, 0, 0, 0);   // A-k0(0) -> buf0
    stage(1, 0, 0, 0);   // B-k0(0)
    stage(0, 1, 0, 0);   // A-k1(0)
    stage(1, 1, 0, 0);   // B-k1(0)
    stage(0, 0, 1, 1);   // A-k0(1) -> buf1
    stage(1, 0, 1, 1);   // B-k0(1)
    asm volatile("s_waitcnt vmcnt(8)" ::: "memory");
    asm volatile("s_barrier" ::: "memory");

    for (int u = 0; u < 16; ++u) {
        int t1 = 2 * u + 1;
        // K-tile 2u (buf0)
        PHASE(0, 0, 0, true,  0, 1, 1, t1,     (void)0)   // stage A-k1(t1)->buf1
        PHASE(0, 1, 0, false, 1, 1, 1, t1,     VM4    )   // stage B-k1(t1)->buf1
        PHASE(0, 0, 1, true,  0, 0, 0, t1 + 1, (void)0)   // stage A-k0(t1+1)->buf0
        PHASE(0, 1, 1, false, 1, 0, 0, t1 + 1, (void)0)   // stage B-k0(t1+1)->buf0
        // K-tile 2u+1 (buf1)
        PHASE(1, 0, 0, true,  0, 1, 0, t1 + 1, (void)0)   // stage A-k1(t1+1)->buf0
        PHASE(1, 1, 0, false, 1, 1, 0, t1 + 1, VM4    )   // stage B-k1(t1+1)->buf0
        PHASE(1, 0, 1, true,  0, 0, 1, t1 + 2, (void)0)   // stage A-k0(t1+2)->buf1
        PHASE(1, 1, 1, false, 1, 0, 1, t1 + 2, (void)0)   // stage B-k0(t1+2)->buf1
    }
#undef PHASE
#undef VM4

    // epilogue: C/D layout col=lane&15, row=(lane>>4)*4+j [m89-verified]
    #pragma unroll
    for (int f = 0; f < 8; ++f) {
        int r = m_blk + wm * 128 + (f >> 2) * 64 + (f & 3) * 16 + (lane >> 4) * 4;
        #pragma unroll
        for (int j = 0; j < 4; ++j) {
            float* cp = C + (size_t)(r + j) * N_N + n_blk + wn * 64 + (lane & 15);
            #pragma unroll
            for (int n = 0; n < 4; ++n)
                cp[n * 16] = acc[f][n][j] * TEMP_INV;
        }
    }
}

// ================= fallback (round-1 fused fp32-staged kernel) ============
__global__ __launch_bounds__(256) void rnorm_kernel(const float* __restrict__ x,
                                                    float* __restrict__ rn) {
    int row = blockIdx.x;
    const float4* xr = reinterpret_cast<const float4*>(x + (size_t)row * D_K);
    int t = threadIdx.x;
    float4 a = xr[t];
    float4 b = xr[t + 256];
    float s = a.x*a.x + a.y*a.y + a.z*a.z + a.w*a.w
            + b.x*b.x + b.y*b.y + b.z*b.z + b.w*b.w;
    #pragma unroll
    for (int off = 32; off > 0; off >>= 1) s += __shfl_down(s, off);
    __shared__ float ps[4];
    int wave = t >> 6, lane = t & 63;
    if (lane == 0) ps[wave] = s;
    __syncthreads();
    if (t == 0) {
        float tot = ps[0] + ps[1] + ps[2] + ps[3];
        rn[row] = 1.0f / fmaxf(sqrtf(tot), 1e-12f);
    }
}

__global__ __launch_bounds__(256, 2) void gemm_kernel(const float* __restrict__ A,
                                                      const float* __restrict__ Bm,
                                                      const float* __restrict__ rn,
                                                      float* __restrict__ C) {
    constexpr int BK = 64;
    __shared__ __align__(16) short lAs[128 * BK];
    __shared__ __align__(16) short lBs[128 * BK];
    int bid = blockIdx.x;
    int nb  = (bid & 7) * 128 + (bid >> 3);
    int tm  = nb & 7;
    int tn  = nb >> 3;
    int m0 = tm * 128, n0 = tn * 128;
    int t = threadIdx.x;
    int lane = t & 63, w = t >> 6;
    int wr = (w >> 1) * 64, wc = (w & 1) * 64;
    f32x4 acc[4][4] = {};
    float4 ra[4][2], rb[4][2];
    float  sc[4];
    int    srow[4], sgrp[4];
    #pragma unroll
    for (int i = 0; i < 4; ++i) {
        int li = t + i * 256;
        srow[i] = li >> 3;
        sgrp[i] = li & 7;
        sc[i]   = rn[m0 + srow[i]];
    }
    auto load_tiles = [&](int kt) {
        int k0 = kt * BK;
        #pragma unroll
        for (int i = 0; i < 4; ++i) {
            const float4* pa = reinterpret_cast<const float4*>(
                A + (size_t)(m0 + srow[i]) * D_K + k0 + sgrp[i] * 8);
            ra[i][0] = pa[0]; ra[i][1] = pa[1];
            const float4* pb = reinterpret_cast<const float4*>(
                Bm + (size_t)(n0 + srow[i]) * D_K + k0 + sgrp[i] * 8);
            rb[i][0] = pb[0]; rb[i][1] = pb[1];
        }
    };
    auto write_tiles = [&]() {
        #pragma unroll
        for (int i = 0; i < 4; ++i) {
            int row = srow[i];
            int slotw = sgrp[i] ^ (row & 7);
            float s = sc[i];
            bf16x8 va, vb;
            va[0] = (short)f2bf(ra[i][0].x * s); va[1] = (short)f2bf(ra[i][0].y * s);
            va[2] = (short)f2bf(ra[i][0].z * s); va[3] = (short)f2bf(ra[i][0].w * s);
            va[4] = (short)f2bf(ra[i][1].x * s); va[5] = (short)f2bf(ra[i][1].y * s);
            va[6] = (short)f2bf(ra[i][1].z * s); va[7] = (short)f2bf(ra[i][1].w * s);
            vb[0] = (short)f2bf(rb[i][0].x); vb[1] = (short)f2bf(rb[i][0].y);
            vb[2] = (short)f2bf(rb[i][0].z); vb[3] = (short)f2bf(rb[i][0].w);
            vb[4] = (short)f2bf(rb[i][1].x); vb[5] = (short)f2bf(rb[i][1].y);
            vb[6] = (short)f2bf(rb[i][1].z); vb[7] = (short)f2bf(rb[i][1].w);
            *reinterpret_cast<bf16x8*>(&lAs[row * BK + slotw * 8]) = va;
            *reinterpret_cast<bf16x8*>(&lBs[row * BK + slotw * 8]) = vb;
        }
    };
    auto compute = [&]() {
        #pragma unroll
        for (int ks = 0; ks < 2; ++ks) {
            bf16x8 af[4], bfr[4];
            #pragma unroll
            for (int f = 0; f < 4; ++f) {
                int arow = wr + f * 16 + (lane & 15);
                int aslot = (ks * 4 + (lane >> 4)) ^ (arow & 7);
                af[f] = *reinterpret_cast<const bf16x8*>(&lAs[arow * BK + aslot * 8]);
                int brow = wc + f * 16 + (lane & 15);
                int bslot = (ks * 4 + (lane >> 4)) ^ (brow & 7);
                bfr[f] = *reinterpret_cast<const bf16x8*>(&lBs[brow * BK + bslot * 8]);
            }
            #pragma unroll
            for (int m = 0; m < 4; ++m)
                #pragma unroll
                for (int n = 0; n < 4; ++n)
                    acc[m][n] = __builtin_amdgcn_mfma_f32_16x16x32_bf16(
                        af[m], bfr[n], acc[m][n], 0, 0, 0);
        }
    };
    load_tiles(0);
    write_tiles();
    for (int kt = 1; kt < D_K / BK; ++kt) {
        __syncthreads();
        load_tiles(kt);
        compute();
        __syncthreads();
        write_tiles();
    }
    __syncthreads();
    compute();
    #pragma unroll
    for (int m = 0; m < 4; ++m) {
        int r = m0 + wr + m * 16 + (lane >> 4) * 4;
        #pragma unroll
        for (int j = 0; j < 4; ++j) {
            float* cp = C + (size_t)(r + j) * N_N + n0 + wc + (lane & 15);
            #pragma unroll
            for (int n = 0; n < 4; ++n)
                cp[n * 16] = acc[m][n][j] * TEMP_INV;
        }
    }
}

extern "C" void kernel_launch(void* const* d_in, const int* in_sizes, int n_in,
                              void* d_out, int out_size, void* d_ws, size_t ws_size,
                              hipStream_t stream) {
    const float* inputs   = (const float*)d_in[0];
    // d_in[1] = targets (unused by the forward output)
    const float* features = (const float*)d_in[2];
    float* out = (float*)d_out;

    const size_t needA = (size_t)M_M * D_K * 2;           // 4 MiB
    const size_t needB = (size_t)N_N * D_K * 2;           // 64 MiB
    if (ws_size >= needA + needB) {
        unsigned short* Abf = (unsigned short*)d_ws;
        unsigned short* Bbf = Abf + (size_t)M_M * D_K;
        prep_kernel<<<M_M + 2048, 256, 0, stream>>>(inputs, features, Abf, Bbf);
        gemm8_kernel<<<(M_M / 256) * (N_N / 256), 512, 0, stream>>>(Abf, Bbf, out);
    } else {
        float* rn = (float*)d_ws;   // 1024 floats
        rnorm_kernel<<<M_M, 256, 0, stream>>>(inputs, rn);
        gemm_kernel<<<(M_M / 128) * (N_N / 128), 256, 0, stream>>>(inputs, features, rn, out);
    }
}

// Round 20
// 103.438 us; speedup vs baseline: 1.0644x; 1.0021x over previous
//
#include <hip/hip_runtime.h>
#include <hip/hip_bf16.h>

// C[1024,16384] = l2norm_rows(inputs[1024,2048]) @ features[16384,2048]^T / 0.05
// Round 19: lock in the best VERIFIED kernel (R16, 103.66 us) after 3
// consecutive infra failures on the unverified 4-phase experiment.
// prep (anorm+bconv fused, HBM-roofline) + 256x256 8-phase GEMM
// (global_load_lds(16), both-sides swizzle, counted vmcnt, setprio).

typedef short bf16x8 __attribute__((ext_vector_type(8)));
typedef float f32x4  __attribute__((ext_vector_type(4)));

#define D_K   2048
#define N_N   16384
#define M_M   1024
#define TEMP_INV 20.0f

__device__ __forceinline__ unsigned short f2bf(float f) {
    unsigned u = __builtin_bit_cast(unsigned, f);
    u += 0x7FFFu + ((u >> 16) & 1u);   // round-to-nearest-even (finite data)
    return (unsigned short)(u >> 16);
}

#define GLOAD16(g, l) __builtin_amdgcn_global_load_lds(                        \
    (const __attribute__((address_space(1))) unsigned int*)(g),                \
    (__attribute__((address_space(3))) unsigned int*)(l), 16, 0, 0)

// ---------------- pass 1: prep = anorm (blocks 0..1023) + bconv (rest) ----
__global__ __launch_bounds__(256) void prep_kernel(const float* __restrict__ x,
                                                   const float* __restrict__ B,
                                                   unsigned short* __restrict__ abf,
                                                   unsigned short* __restrict__ bbf) {
    int t = threadIdx.x;
    if (blockIdx.x < M_M) {
        int row = blockIdx.x;
        const float4* xr = reinterpret_cast<const float4*>(x + (size_t)row * D_K);
        float4 a = xr[t * 2];
        float4 b = xr[t * 2 + 1];
        float s = a.x*a.x + a.y*a.y + a.z*a.z + a.w*a.w
                + b.x*b.x + b.y*b.y + b.z*b.z + b.w*b.w;
        #pragma unroll
        for (int off = 32; off > 0; off >>= 1) s += __shfl_down(s, off);
        __shared__ float ps[4];
        __shared__ float sbc;
        if ((t & 63) == 0) ps[t >> 6] = s;
        __syncthreads();
        if (t == 0) {
            float tot = ps[0] + ps[1] + ps[2] + ps[3];
            sbc = 1.0f / fmaxf(sqrtf(tot), 1e-12f);
        }
        __syncthreads();
        float rs = sbc;
        bf16x8 v;
        v[0] = (short)f2bf(a.x * rs); v[1] = (short)f2bf(a.y * rs);
        v[2] = (short)f2bf(a.z * rs); v[3] = (short)f2bf(a.w * rs);
        v[4] = (short)f2bf(b.x * rs); v[5] = (short)f2bf(b.y * rs);
        v[6] = (short)f2bf(b.z * rs); v[7] = (short)f2bf(b.w * rs);
        *reinterpret_cast<bf16x8*>(abf + (size_t)row * D_K + t * 8) = v;
    } else {
        const size_t nv = (size_t)N_N * D_K / 8;
        size_t stride = (size_t)(gridDim.x - M_M) * blockDim.x;
        for (size_t v = (size_t)(blockIdx.x - M_M) * blockDim.x + t; v < nv; v += stride) {
            const float4* p = reinterpret_cast<const float4*>(B) + v * 2;
            float4 a = p[0], b = p[1];
            bf16x8 o;
            o[0] = (short)f2bf(a.x); o[1] = (short)f2bf(a.y);
            o[2] = (short)f2bf(a.z); o[3] = (short)f2bf(a.w);
            o[4] = (short)f2bf(b.x); o[5] = (short)f2bf(b.y);
            o[6] = (short)f2bf(b.z); o[7] = (short)f2bf(b.w);
            reinterpret_cast<bf16x8*>(bbf)[v] = o;
        }
    }
}

// ---------------- pass 2: 256x256 8-phase GEMM (R16-verified) -------------
// Ledger: 8 stage-ops issued per K-tile (4 stage calls x 2). Single
// vmcnt(4) at P2-post of tile T: 4 newest = k1(T+1) stay; retires k1(T)
// (read T.P3/P4 after barrier) and k0(T+1) (read T+1.P1/P2). k1(T+1) is
// certified by T+1's P2 wait before its P3 read. WAR: every stage targets
// a region >=1 barrier after its last read. Tail clamp -> dead regions.
__global__ __launch_bounds__(512, 2) void gemm8_kernel(const unsigned short* __restrict__ Abf,
                                                       const unsigned short* __restrict__ Bbf,
                                                       float* __restrict__ C) {
    __shared__ __align__(16) unsigned short lds[65536];   // 128 KiB

    // 256 wgs = 4 Mtiles x 64 Ntiles; bijective XCD swizzle (256 % 8 == 0).
    int bid = blockIdx.x;
    int wg  = (bid & 7) * 32 + (bid >> 3);
    int tm  = wg & 3, tn = wg >> 2;
    int m_blk = tm * 256, n_blk = tn * 256;

    int t = threadIdx.x, lane = t & 63, w = t >> 6;
    int wm = w >> 2, wn = w & 3;                     // 2 x 4 wave grid

    // ds_read lane constants: slot = chunk ^ ((row>>1)&3)
    int l15  = lane & 15;
    int slot = ((lane >> 4) ^ ((l15 >> 1) & 3)) * 16;     // byte slot offset
    int aoff = (wm * 128 + l15) * 64 + slot;              // A region byte off
    int boff = (wn * 64  + l15) * 64 + slot;              // B region byte off

    // stage source pointers (pre-swizzled global chunk per rule #21)
    const unsigned short* gA[2];
    const unsigned short* gB[2];
    int sdst[2];
    #pragma unroll
    for (int pass = 0; pass < 2; ++pass) {
        int r = pass * 128 + (t >> 2);
        int csrc = (t & 3) ^ ((r >> 1) & 3);
        gA[pass] = Abf + (size_t)(m_blk + r) * D_K + csrc * 8;
        gB[pass] = Bbf + (size_t)(n_blk + r) * D_K + csrc * 8;
        sdst[pass] = pass * 8192 + w * 1024;   // wave-uniform LDS dest base
    }

    // stage one half-tile: region (mat, s) of K-tile kt into buffer b
    auto stage = [&](int mat, int s, int b, int ktile) {
        int kt = ktile < 32 ? ktile : 31;              // tail clamp (dead regions)
        int koff = kt * 64 + s * 32;
        int ldsb = b * 65536 + mat * 32768 + s * 16384;
        GLOAD16((mat ? gB[0] : gA[0]) + koff, (char*)lds + ldsb + sdst[0]);
        GLOAD16((mat ? gB[1] : gA[1]) + koff, (char*)lds + ldsb + sdst[1]);
    };

    f32x4 acc[8][4] = {};
    bf16x8 bfr[4];                                     // persists across phase pairs

#define VM4 asm volatile("s_waitcnt vmcnt(4)" ::: "memory")

#define PHASE(b, mh, s, LOADB, stMat, stS, stB, stKt, POST)                    \
    {                                                                          \
        bf16x8 af[4];                                                          \
        _Pragma("unroll")                                                      \
        for (int f = 0; f < 4; ++f)                                            \
            af[f] = *reinterpret_cast<const bf16x8*>(                          \
                (char*)lds + (b) * 65536 + (s) * 16384 + aoff +                \
                ((mh) * 64 + f * 16) * 64);                                    \
        if (LOADB) {                                                           \
            _Pragma("unroll")                                                  \
            for (int n = 0; n < 4; ++n)                                        \
                bfr[n] = *reinterpret_cast<const bf16x8*>(                     \
                    (char*)lds + (b) * 65536 + 32768 + (s) * 16384 + boff +    \
                    n * 1024);                                                 \
        }                                                                      \
        stage(stMat, stS, stB, stKt);                                          \
        asm volatile("s_barrier" ::: "memory");                                \
        asm volatile("s_waitcnt lgkmcnt(0)" ::: "memory");                     \
        __builtin_amdgcn_sched_barrier(0);                                     \
        __builtin_amdgcn_s_setprio(1);                                         \
        _Pragma("unroll")                                                      \
        for (int f = 0; f < 4; ++f) {                                          \
            _Pragma("unroll")                                                  \
            for (int n = 0; n < 4; ++n)                                        \
                acc[(mh) * 4 + f][n] = __builtin_amdgcn_mfma_f32_16x16x32_bf16(\
                    af[f], bfr[n], acc[(mh) * 4 + f][n], 0, 0, 0);             \
        }                                                                      \
        __builtin_amdgcn_s_setprio(0);                                         \
        POST;                                                                  \
        asm volatile("s_barrier" ::: "memory");                                \
    }

    // prologue: K0 full + K1 k0-halves; vmcnt(8) -> oldest 4 ops (K0 k0) landed
    stage(0, 0, 0, 0);   // A-k0(0) -> buf0
    stage(1, 0, 0, 0);   // B-k0(0)
    stage(0, 1, 0, 0);   // A-k1(0)
    stage(1, 1, 0, 0);   // B-k1(0)
    stage(0, 0, 1, 1);   // A-k0(1) -> buf1
    stage(1, 0, 1, 1);   // B-k0(1)
    asm volatile("s_waitcnt vmcnt(8)" ::: "memory");
    asm volatile("s_barrier" ::: "memory");

    for (int u = 0; u < 16; ++u) {
        int t1 = 2 * u + 1;
        // K-tile 2u (buf0)
        PHASE(0, 0, 0, true,  0, 1, 1, t1,     (void)0)   // stage A-k1(t1)->buf1
        PHASE(0, 1, 0, false, 1, 1, 1, t1,     VM4    )   // stage B-k1(t1)->buf1
        PHASE(0, 0, 1, true,  0, 0, 0, t1 + 1, (void)0)   // stage A-k0(t1+1)->buf0
        PHASE(0, 1, 1, false, 1, 0, 0, t1 + 1, (void)0)   // stage B-k0(t1+1)->buf0
        // K-tile 2u+1 (buf1)
        PHASE(1, 0, 0, true,  0, 1, 0, t1 + 1, (void)0)   // stage A-k1(t1+1)->buf0
        PHASE(1, 1, 0, false, 1, 1, 0, t1 + 1, VM4    )   // stage B-k1(t1+1)->buf0
        PHASE(1, 0, 1, true,  0, 0, 1, t1 + 2, (void)0)   // stage A-k0(t1+2)->buf1
        PHASE(1, 1, 1, false, 1, 0, 1, t1 + 2, (void)0)   // stage B-k0(t1+2)->buf1
    }
#undef PHASE
#undef VM4

    // epilogue: C/D layout col=lane&15, row=(lane>>4)*4+j [m89-verified]
    #pragma unroll
    for (int f = 0; f < 8; ++f) {
        int r = m_blk + wm * 128 + (f >> 2) * 64 + (f & 3) * 16 + (lane >> 4) * 4;
        #pragma unroll
        for (int j = 0; j < 4; ++j) {
            float* cp = C + (size_t)(r + j) * N_N + n_blk + wn * 64 + (lane & 15);
            #pragma unroll
            for (int n = 0; n < 4; ++n)
                cp[n * 16] = acc[f][n][j] * TEMP_INV;
        }
    }
}

// ================= fallback (round-1 fused fp32-staged kernel) ============
__global__ __launch_bounds__(256) void rnorm_kernel(const float* __restrict__ x,
                                                    float* __restrict__ rn) {
    int row = blockIdx.x;
    const float4* xr = reinterpret_cast<const float4*>(x + (size_t)row * D_K);
    int t = threadIdx.x;
    float4 a = xr[t];
    float4 b = xr[t + 256];
    float s = a.x*a.x + a.y*a.y + a.z*a.z + a.w*a.w
            + b.x*b.x + b.y*b.y + b.z*b.z + b.w*b.w;
    #pragma unroll
    for (int off = 32; off > 0; off >>= 1) s += __shfl_down(s, off);
    __shared__ float ps[4];
    int wave = t >> 6, lane = t & 63;
    if (lane == 0) ps[wave] = s;
    __syncthreads();
    if (t == 0) {
        float tot = ps[0] + ps[1] + ps[2] + ps[3];
        rn[row] = 1.0f / fmaxf(sqrtf(tot), 1e-12f);
    }
}

__global__ __launch_bounds__(256, 2) void gemm_kernel(const float* __restrict__ A,
                                                      const float* __restrict__ Bm,
                                                      const float* __restrict__ rn,
                                                      float* __restrict__ C) {
    constexpr int BK = 64;
    __shared__ __align__(16) short lAs[128 * BK];
    __shared__ __align__(16) short lBs[128 * BK];
    int bid = blockIdx.x;
    int nb  = (bid & 7) * 128 + (bid >> 3);
    int tm  = nb & 7;
    int tn  = nb >> 3;
    int m0 = tm * 128, n0 = tn * 128;
    int t = threadIdx.x;
    int lane = t & 63, w = t >> 6;
    int wr = (w >> 1) * 64, wc = (w & 1) * 64;
    f32x4 acc[4][4] = {};
    float4 ra[4][2], rb[4][2];
    float  sc[4];
    int    srow[4], sgrp[4];
    #pragma unroll
    for (int i = 0; i < 4; ++i) {
        int li = t + i * 256;
        srow[i] = li >> 3;
        sgrp[i] = li & 7;
        sc[i]   = rn[m0 + srow[i]];
    }
    auto load_tiles = [&](int kt) {
        int k0 = kt * BK;
        #pragma unroll
        for (int i = 0; i < 4; ++i) {
            const float4* pa = reinterpret_cast<const float4*>(
                A + (size_t)(m0 + srow[i]) * D_K + k0 + sgrp[i] * 8);
            ra[i][0] = pa[0]; ra[i][1] = pa[1];
            const float4* pb = reinterpret_cast<const float4*>(
                Bm + (size_t)(n0 + srow[i]) * D_K + k0 + sgrp[i] * 8);
            rb[i][0] = pb[0]; rb[i][1] = pb[1];
        }
    };
    auto write_tiles = [&]() {
        #pragma unroll
        for (int i = 0; i < 4; ++i) {
            int row = srow[i];
            int slotw = sgrp[i] ^ (row & 7);
            float s = sc[i];
            bf16x8 va, vb;
            va[0] = (short)f2bf(ra[i][0].x * s); va[1] = (short)f2bf(ra[i][0].y * s);
            va[2] = (short)f2bf(ra[i][0].z * s); va[3] = (short)f2bf(ra[i][0].w * s);
            va[4] = (short)f2bf(ra[i][1].x * s); va[5] = (short)f2bf(ra[i][1].y * s);
            va[6] = (short)f2bf(ra[i][1].z * s); va[7] = (short)f2bf(ra[i][1].w * s);
            vb[0] = (short)f2bf(rb[i][0].x); vb[1] = (short)f2bf(rb[i][0].y);
            vb[2] = (short)f2bf(rb[i][0].z); vb[3] = (short)f2bf(rb[i][0].w);
            vb[4] = (short)f2bf(rb[i][1].x); vb[5] = (short)f2bf(rb[i][1].y);
            vb[6] = (short)f2bf(rb[i][1].z); vb[7] = (short)f2bf(rb[i][1].w);
            *reinterpret_cast<bf16x8*>(&lAs[row * BK + slotw * 8]) = va;
            *reinterpret_cast<bf16x8*>(&lBs[row * BK + slotw * 8]) = vb;
        }
    };
    auto compute = [&]() {
        #pragma unroll
        for (int ks = 0; ks < 2; ++ks) {
            bf16x8 af[4], bfr[4];
            #pragma unroll
            for (int f = 0; f < 4; ++f) {
                int arow = wr + f * 16 + (lane & 15);
                int aslot = (ks * 4 + (lane >> 4)) ^ (arow & 7);
                af[f] = *reinterpret_cast<const bf16x8*>(&lAs[arow * BK + aslot * 8]);
                int brow = wc + f * 16 + (lane & 15);
                int bslot = (ks * 4 + (lane >> 4)) ^ (brow & 7);
                bfr[f] = *reinterpret_cast<const bf16x8*>(&lBs[brow * BK + bslot * 8]);
            }
            #pragma unroll
            for (int m = 0; m < 4; ++m)
                #pragma unroll
                for (int n = 0; n < 4; ++n)
                    acc[m][n] = __builtin_amdgcn_mfma_f32_16x16x32_bf16(
                        af[m], bfr[n], acc[m][n], 0, 0, 0);
        }
    };
    load_tiles(0);
    write_tiles();
    for (int kt = 1; kt < D_K / BK; ++kt) {
        __syncthreads();
        load_tiles(kt);
        compute();
        __syncthreads();
        write_tiles();
    }
    __syncthreads();
    compute();
    #pragma unroll
    for (int m = 0; m < 4; ++m) {
        int r = m0 + wr + m * 16 + (lane >> 4) * 4;
        #pragma unroll
        for (int j = 0; j < 4; ++j) {
            float* cp = C + (size_t)(r + j) * N_N + n0 + wc + (lane & 15);
            #pragma unroll
            for (int n = 0; n < 4; ++n)
                cp[n * 16] = acc[m][n][j] * TEMP_INV;
        }
    }
}

extern "C" void kernel_launch(void* const* d_in, const int* in_sizes, int n_in,
                              void* d_out, int out_size, void* d_ws, size_t ws_size,
                              hipStream_t stream) {
    const float* inputs   = (const float*)d_in[0];
    // d_in[1] = targets (unused by the forward output)
    const float* features = (const float*)d_in[2];
    float* out = (float*)d_out;

    const size_t needA = (size_t)M_M * D_K * 2;           // 4 MiB
    const size_t needB = (size_t)N_N * D_K * 2;           // 64 MiB
    if (ws_size >= needA + needB) {
        unsigned short* Abf = (unsigned short*)d_ws;
        unsigned short* Bbf = Abf + (size_t)M_M * D_K;
        prep_kernel<<<M_M + 2048, 256, 0, stream>>>(inputs, features, Abf, Bbf);
        gemm8_kernel<<<(M_M / 256) * (N_N / 256), 512, 0, stream>>>(Abf, Bbf, out);
    } else {
        float* rn = (float*)d_ws;   // 1024 floats
        rnorm_kernel<<<M_M, 256, 0, stream>>>(inputs, rn);
        gemm_kernel<<<(M_M / 128) * (N_N / 128), 256, 0, stream>>>(inputs, features, rn, out);
    }
}